// Round 8
// baseline (790.846 us; speedup 1.0000x reference)
//
#include <hip/hip_runtime.h>
#include <math.h>

// LSTM B=1024,T=512,IN=16,H=64,OUT=8, gates i,f,g,o.
// R8: REGISTER-RESIDENT recurrence. R5-R7 showed ~1400 cyc/step of stall
// that survived every tweak — all of it tied to the cross-wave structure
// (ds_write -> lgkm drain -> s_barrier release at 1 wave/SIMD -> ds_read).
// This version deletes that structure: ONE wave owns 16 batches end-to-end.
// Gate-row permutation phi(4t+a, rho) = t*64 + 32*(a>>1) + 8*(rho>>2) +
// 4*(a&1) + (rho&3) makes the MFMA C-output of lane (q,m) be exactly the
// h-values that lane must supply as next step's B-fragment (C row=4q+r and
// B k=8q+j live in the same lane column m) -> h: acc -> act -> pkrtz ->
// B-frag entirely in-lane. No LDS, no barriers, no cross-lane ops in the
// 512-step loop. 64 independent waves (64 blocks x 64 thr), self-paced.
// Weights/bias pinned in VGPRs (~400 regs; launch_bounds(64,1) -> 512 cap).
// x: per-lane global float4 pairs, 2 steps ahead, ping-pong regs.

#define LSTM_T 512
#define LSTM_IN 16
#define LSTM_H 64
#define LSTM_OUT 8
#define BT 16

#define L2E   1.44269504088896340736f
#define L2E2  2.88539008177792681472f

typedef _Float16 half8  __attribute__((ext_vector_type(8)));
typedef float    floatx4 __attribute__((ext_vector_type(4)));

static __device__ __forceinline__ float fast_rcp(float x) { return __builtin_amdgcn_rcpf(x); }
static __device__ __forceinline__ float fast_exp2(float x) { return __builtin_amdgcn_exp2f(x); }
static __device__ __forceinline__ float sigm2(float p) { return fast_rcp(1.0f + fast_exp2(-p)); }
static __device__ __forceinline__ float tanh2(float p) {
    return fmaf(-2.0f, fast_rcp(1.0f + fast_exp2(p)), 1.0f);
}
static __device__ __forceinline__ void pin4(int4& v) {
    asm volatile("" : "+v"(v.x), "+v"(v.y), "+v"(v.z), "+v"(v.w));
}
static __device__ __forceinline__ void pinf4(float4& v) {
    asm volatile("" : "+v"(v.x), "+v"(v.y), "+v"(v.z), "+v"(v.w));
}
static __device__ __forceinline__ unsigned pk2h(float a, float b) {
    return __builtin_bit_cast(unsigned, __builtin_amdgcn_cvt_pkrtz(a, b));
}
static __device__ __forceinline__ half8 to_h8(float4 a, float4 b) {
    uint4 u = make_uint4(pk2h(a.x, a.y), pk2h(a.z, a.w), pk2h(b.x, b.y), pk2h(b.z, b.w));
    return __builtin_bit_cast(half8, u);
}
static __device__ __forceinline__ int4 cvt8h(float4 a, float4 b, float sc) {
    float4 as = make_float4(a.x * sc, a.y * sc, a.z * sc, a.w * sc);
    float4 bs = make_float4(b.x * sc, b.y * sc, b.z * sc, b.w * sc);
    return __builtin_bit_cast(int4, to_h8(as, bs));
}
static __device__ __forceinline__ float4 ld4(const float* p) {
    return *reinterpret_cast<const float4*>(p);
}

__global__ __launch_bounds__(64, 1)
void lstm_wave_kernel(const float* __restrict__ x,
                      const float* __restrict__ W_ih,
                      const float* __restrict__ W_hh,
                      const float* __restrict__ b_ih,
                      const float* __restrict__ b_hh,
                      const float* __restrict__ W_fc,
                      const float* __restrict__ b_fc,
                      float* __restrict__ out) {
    const int lane  = threadIdx.x;     // single wave per block
    const int q     = lane >> 4;       // k-quad / C row group
    const int m     = lane & 15;       // A row slot / B col / C col (batch)
    const int bbase = blockIdx.x * BT;

    __shared__ __align__(16) float hfin[BT][LSTM_H];   // final h only (epilogue)

    // ---- weights as pinned fp16 A-fragments under the phi permutation ----
    // tile tt = 4t+a; A row slot rho -> gate phi = t*64 + psi(a, rho>>2, rho&3)
    // with psi(a,q,r) = 32*(a>>1) + 8q + 4*(a&1) + r.
    int4 Ahh[16][2];   // W_hh, K-chunks k=[0,32),[32,64)
    int4 Ax[16];       // W_ih, k=[0,16) real, rest zero
    float4 bias4[16];  // C-init (rows 4q+r)
    #pragma unroll
    for (int tt = 0; tt < 16; ++tt) {
        const int t_ = tt >> 2, a = tt & 3;
        const float sc = (t_ == 2) ? L2E2 : L2E;
        const int ga = t_ * 64 + 32 * (a >> 1) + 8 * (m >> 2) + 4 * (a & 1) + (m & 3);
        #pragma unroll
        for (int c = 0; c < 2; ++c) {
            const float* s = W_hh + ga * LSTM_H + 32 * c + 8 * q;
            Ahh[tt][c] = cvt8h(ld4(s), ld4(s + 4), sc);
            pin4(Ahh[tt][c]);
        }
        float4 xa = make_float4(0.f, 0.f, 0.f, 0.f), xb = xa;
        if (q < 2) {
            const float* s = W_ih + ga * LSTM_IN + 8 * q;
            xa = ld4(s); xb = ld4(s + 4);
        }
        Ax[tt] = cvt8h(xa, xb, sc);
        pin4(Ax[tt]);
        const int gb = t_ * 64 + 32 * (a >> 1) + 8 * q + 4 * (a & 1);
        float4 bi = ld4(b_ih + gb), bh = ld4(b_hh + gb);
        bias4[tt] = make_float4((bi.x + bh.x) * sc, (bi.y + bh.y) * sc,
                                (bi.z + bh.z) * sc, (bi.w + bh.w) * sc);
        pinf4(bias4[tt]);
    }

    // ---- x pipeline: per-lane (batch m), elements 8q..8q+7 (q<2 real) ----
    const float* xp = x + (size_t)(bbase + m) * LSTM_T * LSTM_IN + 8 * q;
    float4 xc0 = make_float4(0.f, 0.f, 0.f, 0.f), xc1 = xc0, xl0 = xc0, xl1 = xc0;
    if (q < 2) { xc0 = ld4(xp); xc1 = ld4(xp + 4); }          // x_0

    floatx4 acc[16];
    {   // acc = bias + W_ih . x_0   (pre-x for step 0)
        half8 xf = to_h8(xc0, xc1);
        #pragma unroll
        for (int tt = 0; tt < 16; ++tt)
            acc[tt] = __builtin_amdgcn_mfma_f32_16x16x32_f16(
                __builtin_bit_cast(half8, Ax[tt]), xf,
                __builtin_bit_cast(floatx4, bias4[tt]), 0, 0, 0);
    }
    if (q < 2) { xc0 = ld4(xp + LSTM_IN); xc1 = ld4(xp + LSTM_IN + 4); }  // x_1

    half8 bfr0 = {}, bfr1 = {};        // h_{t-1} B-frags (h_{-1} = 0)
    float creg[16];
    float hf[4][4];
    #pragma unroll
    for (int i = 0; i < 16; ++i) creg[i] = 0.f;

#define STEP(T_, CUR0, CUR1, NXT0, NXT1)                                        \
    {                                                                           \
        if (q < 2) {   /* load x_{t+2} (clamped; ~1 full step of slack) */      \
            int tn = (T_) + 2 < LSTM_T ? (T_) + 2 : LSTM_T - 1;                 \
            NXT0 = ld4(xp + (size_t)tn * LSTM_IN);                              \
            NXT1 = ld4(xp + (size_t)tn * LSTM_IN + 4);                          \
        }                                                                       \
        _Pragma("unroll")                                                       \
        for (int tt = 0; tt < 16; ++tt)                                         \
            acc[tt] = __builtin_amdgcn_mfma_f32_16x16x32_f16(                   \
                __builtin_bit_cast(half8, Ahh[tt][0]), bfr0, acc[tt], 0, 0, 0); \
        _Pragma("unroll")                                                       \
        for (int tt = 0; tt < 16; ++tt)                                         \
            acc[tt] = __builtin_amdgcn_mfma_f32_16x16x32_f16(                   \
                __builtin_bit_cast(half8, Ahh[tt][1]), bfr1, acc[tt], 0, 0, 0); \
        _Pragma("unroll")                                                       \
        for (int a = 0; a < 4; ++a) {                                           \
            _Pragma("unroll")                                                   \
            for (int r = 0; r < 4; ++r) {                                       \
                float gi = sigm2(acc[a][r]);                                    \
                float gf = sigm2(acc[4 + a][r]);                                \
                float gg = tanh2(acc[8 + a][r]);                                \
                float go = sigm2(acc[12 + a][r]);                               \
                float cc = fmaf(gf, creg[4 * a + r], gi * gg);                  \
                creg[4 * a + r] = cc;                                           \
                hf[a][r] = go * tanh2(cc * L2E2);                               \
            }                                                                   \
        }                                                                       \
        {   /* pack h -> next B-frags (in-lane, the phi-permutation payoff) */  \
            uint4 u0 = make_uint4(pk2h(hf[0][0], hf[0][1]), pk2h(hf[0][2], hf[0][3]), \
                                  pk2h(hf[1][0], hf[1][1]), pk2h(hf[1][2], hf[1][3])); \
            uint4 u1 = make_uint4(pk2h(hf[2][0], hf[2][1]), pk2h(hf[2][2], hf[2][3]), \
                                  pk2h(hf[3][0], hf[3][1]), pk2h(hf[3][2], hf[3][3])); \
            bfr0 = __builtin_bit_cast(half8, u0);                               \
            bfr1 = __builtin_bit_cast(half8, u1);                               \
        }                                                                       \
        {   /* pre-x for step t+1: acc = bias + W_ih . x_{t+1} */               \
            half8 xf = to_h8(CUR0, CUR1);                                       \
            _Pragma("unroll")                                                   \
            for (int tt = 0; tt < 16; ++tt)                                     \
                acc[tt] = __builtin_amdgcn_mfma_f32_16x16x32_f16(               \
                    __builtin_bit_cast(half8, Ax[tt]), xf,                      \
                    __builtin_bit_cast(floatx4, bias4[tt]), 0, 0, 0);           \
        }                                                                       \
    }

    for (int t = 0; t < LSTM_T; t += 2) {
        STEP(t,     xc0, xc1, xl0, xl1)    // x-MFMA consumes x_{t+1}=xc, loads x_{t+2}->xl
        STEP(t + 1, xl0, xl1, xc0, xc1)    // consumes x_{t+2}=xl, loads x_{t+3}->xc
    }
#undef STEP

    // ---- epilogue: final h -> LDS (same wave), FC + sigmoid ----
    #pragma unroll
    for (int a = 0; a < 4; ++a) {
        int j0 = 32 * (a >> 1) + 8 * q + 4 * (a & 1);
        *reinterpret_cast<float4*>(&hfin[m][j0]) =
            make_float4(hf[a][0], hf[a][1], hf[a][2], hf[a][3]);
    }
    __syncthreads();   // single wave: trivial; orders LDS writes before reads

    {   // 128 outputs over 64 lanes: lane -> batch lane>>2, outputs 2*(lane&3)+{0,1}
        int b = lane >> 2;
        #pragma unroll
        for (int s = 0; s < 2; ++s) {
            int o = (lane & 3) * 2 + s;
            float sacc = b_fc[o];
            #pragma unroll
            for (int j4 = 0; j4 < LSTM_H / 4; ++j4) {
                float4 wv = ld4(W_fc + o * LSTM_H + 4 * j4);
                float4 hv = *reinterpret_cast<const float4*>(&hfin[b][4 * j4]);
                sacc = fmaf(wv.x, hv.x, sacc);
                sacc = fmaf(wv.y, hv.y, sacc);
                sacc = fmaf(wv.z, hv.z, sacc);
                sacc = fmaf(wv.w, hv.w, sacc);
            }
            out[(size_t)(bbase + b) * LSTM_OUT + o] = sigm2(sacc * L2E);
        }
    }
}

extern "C" void kernel_launch(void* const* d_in, const int* in_sizes, int n_in,
                              void* d_out, int out_size, void* d_ws, size_t ws_size,
                              hipStream_t stream) {
    const float* x    = (const float*)d_in[0];
    const float* W_ih = (const float*)d_in[1];
    const float* W_hh = (const float*)d_in[2];
    const float* b_ih = (const float*)d_in[3];
    const float* b_hh = (const float*)d_in[4];
    const float* W_fc = (const float*)d_in[5];
    const float* b_fc = (const float*)d_in[6];
    float* out = (float*)d_out;

    lstm_wave_kernel<<<1024 / BT, 64, 0, stream>>>(
        x, W_ih, W_hh, b_ih, b_hh, W_fc, b_fc, out);
}

// Round 9
// 267.530 us; speedup vs baseline: 2.9561x; 2.9561x over previous
//
#include <hip/hip_runtime.h>
#include <math.h>

// LSTM B=1024,T=512,IN=16,H=64,OUT=8, gates i,f,g,o.
// R9: REVISED HW MODEL from R8's failure: v_exp/v_rcp wave64 issue ~16cyc
// (quarter-rate trans pipe). R5's 1430 cyc/step = 640 trans + 270 other +
// ~500 latency; R8 concentrated 4x trans on one wave -> 3640 ✓ model.
// Fix = SPREAD: BT=4 -> 256 blocks (every CU), and the 16 MFMA cols hold
// each batch 4x replicated -> the 4 replica lanes (rho=m>>2) hold identical
// C-frags, so replica rho activates only row r=rho: 1 (j,b) pair per lane.
// Trans issue 640 -> 160 cyc/wave-step. Structure else = proven R5/R6:
// wave w owns j-slice [16w,16w+16), tiles tt = gate type, fp16 weights
// pinned in regs, h via double-buffered LDS (stride 72 halves), 1 lite
// barrier/step (h flows through LDS -> lgkmcnt suffices).

#define LSTM_T 512
#define LSTM_IN 16
#define LSTM_H 64
#define LSTM_OUT 8
#define BT 4
#define HSTRIDE 72         // halves per batch row: 64 h + 8 pad (bank spread)

#define L2E   1.44269504088896340736f
#define L2E2  2.88539008177792681472f

typedef _Float16 half8  __attribute__((ext_vector_type(8)));
typedef float    floatx4 __attribute__((ext_vector_type(4)));

static __device__ __forceinline__ float fast_rcp(float x) { return __builtin_amdgcn_rcpf(x); }
static __device__ __forceinline__ float fast_exp2(float x) { return __builtin_amdgcn_exp2f(x); }
static __device__ __forceinline__ float sigm2(float p) { return fast_rcp(1.0f + fast_exp2(-p)); }
static __device__ __forceinline__ float tanh2(float p) {
    return fmaf(-2.0f, fast_rcp(1.0f + fast_exp2(p)), 1.0f);
}
static __device__ __forceinline__ void pin4(int4& v) {
    asm volatile("" : "+v"(v.x), "+v"(v.y), "+v"(v.z), "+v"(v.w));
}
static __device__ __forceinline__ void pinf4(float4& v) {
    asm volatile("" : "+v"(v.x), "+v"(v.y), "+v"(v.z), "+v"(v.w));
}
static __device__ __forceinline__ void lite_barrier() {
    asm volatile("s_waitcnt lgkmcnt(0)\n\ts_barrier" ::: "memory");
}
static __device__ __forceinline__ unsigned pk2h(float a, float b) {
    return __builtin_bit_cast(unsigned, __builtin_amdgcn_cvt_pkrtz(a, b));
}
static __device__ __forceinline__ half8 to_h8(float4 a, float4 b) {
    uint4 u = make_uint4(pk2h(a.x, a.y), pk2h(a.z, a.w), pk2h(b.x, b.y), pk2h(b.z, b.w));
    return __builtin_bit_cast(half8, u);
}
static __device__ __forceinline__ int4 cvt8h(float4 a, float4 b, float sc) {
    float4 as = make_float4(a.x * sc, a.y * sc, a.z * sc, a.w * sc);
    float4 bs = make_float4(b.x * sc, b.y * sc, b.z * sc, b.w * sc);
    return __builtin_bit_cast(int4, to_h8(as, bs));
}
static __device__ __forceinline__ float4 ld4(const float* p) {
    return *reinterpret_cast<const float4*>(p);
}
// select element rho (0..3) of a float4-vector via 3 cndmasks
static __device__ __forceinline__ float sel4(floatx4 v, bool r0, bool r1) {
    float lo = r0 ? v[1] : v[0];
    float hi = r0 ? v[3] : v[2];
    return r1 ? hi : lo;
}

__global__ __launch_bounds__(256, 1)
void lstm_mfma_kernel(const float* __restrict__ x,
                      const float* __restrict__ W_ih,
                      const float* __restrict__ W_hh,
                      const float* __restrict__ b_ih,
                      const float* __restrict__ b_hh,
                      const float* __restrict__ W_fc,
                      const float* __restrict__ b_fc,
                      float* __restrict__ out) {
    const int tid   = threadIdx.x;
    const int lane  = tid & 63;
    const int w     = tid >> 6;        // wave -> j-slice [16w, 16w+16)
    const int q     = lane >> 4;       // k-quad / C row group
    const int m     = lane & 15;       // A row-in-tile / B col / C col
    const int b     = m & 3;           // real batch (cols replicated 4x)
    const int rho   = m >> 2;          // replica id -> which C row r to activate
    const bool r0   = (rho & 1) != 0;
    const bool r1   = (rho & 2) != 0;
    const int jmine = 16 * w + 4 * q + rho;   // this lane's hidden index
    const int bbase = blockIdx.x * BT;

    __shared__ __align__(16) _Float16 hbuf[2][BT][HSTRIDE];  // h state, dbuf
    __shared__ __align__(16) float hfin[BT][LSTM_H];         // final h for FC

    // ---- weights as pinned fp16 A-fragments, log2e folded ----
    // tile tt = gate type; A row = tt*64 + 16w + m.
    int4 Ah[4][2], Ax[4];
    float4 bias4[4];
    #pragma unroll
    for (int tt = 0; tt < 4; ++tt) {
        const float sc = (tt == 2) ? L2E2 : L2E;
        const int gt = tt * 64 + 16 * w + m;
        #pragma unroll
        for (int c = 0; c < 2; ++c) {
            const float* s = W_hh + gt * LSTM_H + 32 * c + 8 * q;
            Ah[tt][c] = cvt8h(ld4(s), ld4(s + 4), sc);
            pin4(Ah[tt][c]);
        }
        float4 xa = make_float4(0.f, 0.f, 0.f, 0.f), xb = xa;
        if (q < 2) {
            const float* s = W_ih + gt * LSTM_IN + 8 * q;
            xa = ld4(s); xb = ld4(s + 4);
        }
        Ax[tt] = cvt8h(xa, xb, sc);
        pin4(Ax[tt]);
        const int gb = tt * 64 + 16 * w + 4 * q;
        float4 bi = ld4(b_ih + gb), bh = ld4(b_hh + gb);
        bias4[tt] = make_float4((bi.x + bh.x) * sc, (bi.y + bh.y) * sc,
                                (bi.z + bh.z) * sc, (bi.w + bh.w) * sc);
        pinf4(bias4[tt]);
    }

    // ---- zero hbuf[0] h-region (h_{-1} = 0): 4*64 halves = 128 ints ----
    if (tid < 128) {
        int bb = tid >> 5, jj = tid & 31;
        reinterpret_cast<int*>(&hbuf[0][bb][0])[jj] = 0;
    }

    // ---- x: lane covers batch b, elements 8q..8q+7 (q<2 real) ----
    const float* xp = x + (size_t)(bbase + b) * LSTM_T * LSTM_IN + 8 * q;
    float4 xA0 = make_float4(0.f, 0.f, 0.f, 0.f), xA1 = xA0;  // even steps
    float4 xB0 = xA0, xB1 = xA0;                              // odd steps
    if (q < 2) {
        xA0 = ld4(xp);              xA1 = ld4(xp + 4);               // x_0
        xB0 = ld4(xp + LSTM_IN);    xB1 = ld4(xp + LSTM_IN + 4);     // x_1
    }
    __syncthreads();   // hbuf zeros visible

    float creg = 0.0f, hreg = 0.0f;

#define STEP(T_, X0, X1)                                                        \
    {                                                                           \
        const _Float16* cur = &hbuf[(T_) & 1][0][0];                            \
        _Float16*       nxt = &hbuf[((T_) + 1) & 1][0][0];                      \
        /* h_{t-1} B-frags (col m = batch b) */                                 \
        half8 bh0 = *reinterpret_cast<const half8*>(cur + b * HSTRIDE + 8 * q); \
        half8 bh1 = *reinterpret_cast<const half8*>(cur + b * HSTRIDE + 32 + 8 * q); \
        /* acc = bias + W_ih . x_t (independent of h -> hides under ds_read) */ \
        half8 xf = to_h8(X0, X1);                                               \
        floatx4 acc[4];                                                         \
        _Pragma("unroll")                                                       \
        for (int tt = 0; tt < 4; ++tt)                                          \
            acc[tt] = __builtin_amdgcn_mfma_f32_16x16x32_f16(                   \
                __builtin_bit_cast(half8, Ax[tt]), xf,                          \
                __builtin_bit_cast(floatx4, bias4[tt]), 0, 0, 0);               \
        /* reload this reg set with x_{t+2} (2 steps of slack) */               \
        if (q < 2 && (T_) + 2 < LSTM_T) {                                       \
            X0 = ld4(xp + (size_t)((T_) + 2) * LSTM_IN);                        \
            X1 = ld4(xp + (size_t)((T_) + 2) * LSTM_IN + 4);                    \
        }                                                                       \
        _Pragma("unroll")                                                       \
        for (int tt = 0; tt < 4; ++tt)                                          \
            acc[tt] = __builtin_amdgcn_mfma_f32_16x16x32_f16(                   \
                __builtin_bit_cast(half8, Ah[tt][0]), bh0, acc[tt], 0, 0, 0);   \
        _Pragma("unroll")                                                       \
        for (int tt = 0; tt < 4; ++tt)                                          \
            acc[tt] = __builtin_amdgcn_mfma_f32_16x16x32_f16(                   \
                __builtin_bit_cast(half8, Ah[tt][1]), bh1, acc[tt], 0, 0, 0);   \
        /* replica rho activates ONLY row r=rho: 1 (j,b) pair per lane */       \
        float gi = sigm2(sel4(acc[0], r0, r1));                                 \
        float gf = sigm2(sel4(acc[1], r0, r1));                                 \
        float gg = tanh2(sel4(acc[2], r0, r1));                                 \
        float go = sigm2(sel4(acc[3], r0, r1));                                 \
        creg = fmaf(gf, creg, gi * gg);                                         \
        hreg = go * tanh2(creg * L2E2);                                         \
        /* h -> next buffer: each (j,b) written by exactly one lane */          \
        nxt[b * HSTRIDE + jmine] = (_Float16)hreg;                              \
        lite_barrier();                                                         \
    }

    for (int t = 0; t < LSTM_T; t += 2) {
        STEP(t,     xA0, xA1)
        STEP(t + 1, xB0, xB1)
    }
#undef STEP

    // ---- final h (fp32) -> LDS, then FC + sigmoid ----
    hfin[b][jmine] = hreg;
    __syncthreads();

    if (tid < BT * LSTM_OUT) {
        int bb = tid >> 3, o = tid & 7;
        float s = b_fc[o];
        #pragma unroll
        for (int j4 = 0; j4 < LSTM_H / 4; ++j4) {
            float4 wv = ld4(W_fc + o * LSTM_H + 4 * j4);
            float4 hv = *reinterpret_cast<const float4*>(&hfin[bb][4 * j4]);
            s = fmaf(wv.x, hv.x, s);
            s = fmaf(wv.y, hv.y, s);
            s = fmaf(wv.z, hv.z, s);
            s = fmaf(wv.w, hv.w, s);
        }
        out[(size_t)(bbase + bb) * LSTM_OUT + o] = sigm2(s * L2E);
    }
}

extern "C" void kernel_launch(void* const* d_in, const int* in_sizes, int n_in,
                              void* d_out, int out_size, void* d_ws, size_t ws_size,
                              hipStream_t stream) {
    const float* x    = (const float*)d_in[0];
    const float* W_ih = (const float*)d_in[1];
    const float* W_hh = (const float*)d_in[2];
    const float* b_ih = (const float*)d_in[3];
    const float* b_hh = (const float*)d_in[4];
    const float* W_fc = (const float*)d_in[5];
    const float* b_fc = (const float*)d_in[6];
    float* out = (float*)d_out;

    lstm_mfma_kernel<<<1024 / BT, 256, 0, stream>>>(
        x, W_ih, W_hh, b_ih, b_hh, W_fc, b_fc, out);
}